// Round 5
// baseline (691.224 us; speedup 1.0000x reference)
//
#include <hip/hip_runtime.h>
#include <cstdint>
#include <cstddef>

#define LN_EPS 1e-5f

typedef short bf16x8 __attribute__((ext_vector_type(8)));
typedef float f32x4 __attribute__((ext_vector_type(4)));

__device__ __forceinline__ uint16_t f2bf(float f){
  uint32_t u = __float_as_uint(f);
  u += 0x7fffu + ((u >> 16) & 1u);
  return (uint16_t)(u >> 16);
}
__device__ __forceinline__ float bf2f(uint16_t h){
  return __uint_as_float(((uint32_t)h) << 16);
}
__device__ __forceinline__ float sigm(float x){
  return __builtin_amdgcn_rcpf(1.0f + __expf(-x));
}

// ---------------- K0: convert 6 weight matrices (128x128 fp32) to bf16 ----------------
// order: 0=left_proj_w 1=left_gate_w 2=right_proj_w 3=right_gate_w 4=gating_w 5=out_proj_w
__global__ __launch_bounds__(256) void wconv_k(
    const float* __restrict__ w0, const float* __restrict__ w1,
    const float* __restrict__ w2, const float* __restrict__ w3,
    const float* __restrict__ w4, const float* __restrict__ w5,
    uint16_t* __restrict__ dst)
{
  int i = blockIdx.x*256 + threadIdx.x;   // 6*16384 total
  int m = i >> 14, e = i & 16383;
  const float* s = (m==0)?w0:(m==1)?w1:(m==2)?w2:(m==3)?w3:(m==4)?w4:w5;
  dst[i] = f2bf(s[e]);
}

// ---------------- K1: LN + 5 projections, wave-specialized, W-in-registers ----------------
// 1024 blocks x 768 threads (12 waves); block owns 256 rows as 4 tiles of 64.
// Waves 0-3: left proj+gate; 4-7: right; 8-11: gating + LN of next tile (sum/norm split,
// act re-read from L1 in norm pass -> no 32-reg spill).
// Single sA (16KB) + single sT (48KB) => ~64.5KB LDS => 2 blocks/CU (24 waves).
__global__ __launch_bounds__(768, 6) void k1_proj(
    const float* __restrict__ act, const float* __restrict__ mask,
    const float* __restrict__ lnw, const float* __restrict__ lnb,
    const float* __restrict__ lpb, const float* __restrict__ lgB,
    const float* __restrict__ rpb, const float* __restrict__ rgB,
    const float* __restrict__ gB,
    const uint16_t* __restrict__ wbf,
    uint16_t* __restrict__ leftT, uint16_t* __restrict__ rightT,
    uint16_t* __restrict__ gbuf)
{
  __shared__ uint16_t sA[64*128];     // 16KB [row64][c128] bf16 swizzled
  __shared__ uint16_t sT[3*128*64];   // 48KB [c128][p64] bf16 swizzled, per family
  __shared__ float sMask[64];
  const int t = threadIdx.x;
  const int lane = t & 63, wid = t >> 6;
  const int p0 = blockIdx.x * 256;
  const int l15 = lane & 15, lh = lane >> 4;
  const bool isG = (wid >= 8);
  const int fam = wid >> 2;               // 0=L, 1=R, 2=G
  const int cbase = (wid & 3) * 32;
  const f32x4 z4 = {0.f,0.f,0.f,0.f};

  // ---- persistent W fragments (loaded once) ----
  bf16x8 Wp[2][4], Wg[2][4];
  {
    const int m0 = (fam==0)?0:(fam==1)?2:4;
#pragma unroll
    for(int tn=0;tn<2;tn++){
      const int o = cbase + tn*16 + l15;
#pragma unroll
      for(int ks=0;ks<4;ks++)
        Wp[tn][ks] = *(const bf16x8*)(wbf + m0*16384 + o*128 + ks*32 + lh*8);
    }
    if(!isG){
#pragma unroll
      for(int tn=0;tn<2;tn++){
        const int o = cbase + tn*16 + l15;
#pragma unroll
        for(int ks=0;ks<4;ks++)
          Wg[tn][ks] = *(const bf16x8*)(wbf + (m0+1)*16384 + o*128 + ks*32 + lh*8);
      }
    }
  }
  // ---- biases (persistent scalars) ----
  float pbv[2], gbv[2];
  {
    const float* pb  = (fam==0)? lpb : (fam==1)? rpb : gB;
    const float* gb2 = (fam==0)? lgB : rgB;
#pragma unroll
    for(int tn=0;tn<2;tn++){
      const int c = cbase + tn*16 + l15;
      pbv[tn] = pb[c];
      gbv[tn] = isG ? 0.f : gb2[c];
    }
  }

  // ---- G-wave LN: sum pass (keeps only s,s2,mv) ----
  auto ln_sum = [&](int tile, float& s, float& s2, float& mv){
    const int g = t - 512, row = g >> 2, q = g & 3;
    const float* src = act + (size_t)(p0 + tile*64 + row)*128 + q*32;
    s = 0.f; s2 = 0.f;
#pragma unroll
    for(int u=0;u<8;u++){
      float4 v = *(const float4*)(src + u*4);
      s  += v.x + v.y + v.z + v.w;
      s2 += v.x*v.x + v.y*v.y + v.z*v.z + v.w*v.w;
    }
    s  += __shfl_xor(s,1);  s  += __shfl_xor(s,2);
    s2 += __shfl_xor(s2,1); s2 += __shfl_xor(s2,2);
    if(q==0) mv = mask[p0 + tile*64 + row];
  };
  // ---- G-wave LN: normalize pass (re-reads act from L1) ----
  auto ln_norm = [&](int tile, float s, float s2, float mv){
    const int g = t - 512, row = g >> 2, q = g & 3;
    const float* src = act + (size_t)(p0 + tile*64 + row)*128 + q*32;
    const float mu   = s * (1.f/128.f);
    const float var  = s2 * (1.f/128.f) - mu*mu;
    const float rstd = rsqrtf(var + LN_EPS);
    const int rs = (row&7)<<4;
#pragma unroll
    for(int u=0;u<4;u++){
      const int c0 = q*32 + u*8;
      float4 a0 = *(const float4*)(src + u*8);
      float4 a1 = *(const float4*)(src + u*8 + 4);
      float4 w0 = *(const float4*)(lnw + c0), w1 = *(const float4*)(lnw + c0 + 4);
      float4 b0 = *(const float4*)(lnb + c0), b1 = *(const float4*)(lnb + c0 + 4);
      uint16_t h[8];
      h[0]=f2bf((a0.x-mu)*rstd*w0.x+b0.x); h[1]=f2bf((a0.y-mu)*rstd*w0.y+b0.y);
      h[2]=f2bf((a0.z-mu)*rstd*w0.z+b0.z); h[3]=f2bf((a0.w-mu)*rstd*w0.w+b0.w);
      h[4]=f2bf((a1.x-mu)*rstd*w1.x+b1.x); h[5]=f2bf((a1.y-mu)*rstd*w1.y+b1.y);
      h[6]=f2bf((a1.z-mu)*rstd*w1.z+b1.z); h[7]=f2bf((a1.w-mu)*rstd*w1.w+b1.w);
      uint4 pk;
      pk.x = (uint32_t)h[0] | ((uint32_t)h[1]<<16);
      pk.y = (uint32_t)h[2] | ((uint32_t)h[3]<<16);
      pk.z = (uint32_t)h[4] | ((uint32_t)h[5]<<16);
      pk.w = (uint32_t)h[6] | ((uint32_t)h[7]<<16);
      *(uint4*)((char*)sA + row*256 + ((c0*2) ^ rs)) = pk;
    }
    if(q==0) sMask[row] = mv;
  };

  // ---- gemm + fused epilogue for one 64-row tile ----
  auto work = [&](){
    uint16_t* sTf = sT + fam*8192;
#pragma unroll
    for(int rt=0; rt<4; rt++){
      bf16x8 af[4];
      const int arow = rt*16 + l15;
      const int ars = (arow&7)<<4;
#pragma unroll
      for(int ks=0;ks<4;ks++)
        af[ks] = *(const bf16x8*)((const char*)sA + arow*256 + ((ks*64+lh*16) ^ ars));
      f32x4 aP[2] = {z4,z4}, aQ[2] = {z4,z4};
      if(isG){
#pragma unroll
        for(int ks=0;ks<4;ks++)
#pragma unroll
          for(int tn=0;tn<2;tn++)
            aP[tn] = __builtin_amdgcn_mfma_f32_16x16x32_bf16(af[ks], Wp[tn][ks], aP[tn], 0,0,0);
      } else {
#pragma unroll
        for(int ks=0;ks<4;ks++)
#pragma unroll
          for(int tn=0;tn<2;tn++){
            aP[tn] = __builtin_amdgcn_mfma_f32_16x16x32_bf16(af[ks], Wp[tn][ks], aP[tn], 0,0,0);
            aQ[tn] = __builtin_amdgcn_mfma_f32_16x16x32_bf16(af[ks], Wg[tn][ks], aQ[tn], 0,0,0);
          }
      }
      const int prow = rt*16 + lh*4;
      const int poff = prow*2;
#pragma unroll
      for(int tn=0;tn<2;tn++){
        const int c = cbase + tn*16 + l15;
        uint16_t h[4];
        if(isG){
#pragma unroll
          for(int r=0;r<4;r++)
            h[r] = f2bf(sigm(aP[tn][r] + pbv[tn]));
        } else {
#pragma unroll
          for(int r=0;r<4;r++)
            h[r] = f2bf(sMask[prow+r]*(aP[tn][r]+pbv[tn]) * sigm(aQ[tn][r]+gbv[tn]));
        }
        uint2 pk;
        pk.x = (uint32_t)h[0] | ((uint32_t)h[1]<<16);
        pk.y = (uint32_t)h[2] | ((uint32_t)h[3]<<16);
        *(uint2*)((char*)sTf + c*128 + (poff ^ ((c&7)<<4))) = pk;
      }
    }
  };

  // ---- coalesced c-major readout of sT (all 12 waves) ----
  auto readout = [&](int pbase){
    const int oi = t >> 8;                // 0=L,1=R,2=G
    const int c = (t >> 1) & 127;
    const int ph = (t & 1) * 32;
    const int cs = (c&7) << 4;
    const char* src = (const char*)(sT + oi*8192);
    uint4 q[4];
#pragma unroll
    for(int u=0;u<4;u++)
      q[u] = *(const uint4*)(src + c*128 + ((ph*2 + u*16) ^ cs));
    uint16_t* base = (oi==0)? leftT : (oi==1)? rightT : gbuf;
    uint16_t* dst = base + (size_t)c*262144 + pbase + ph;
    *(uint4*)(dst+ 0)=q[0]; *(uint4*)(dst+ 8)=q[1];
    *(uint4*)(dst+16)=q[2]; *(uint4*)(dst+24)=q[3];
  };

  float s_a = 0.f, s2_a = 0.f, mv_a = 0.f;

  // ---- prologue: G waves LN tile 0 ----
  if(isG){
    ln_sum(0, s_a, s2_a, mv_a);
    ln_norm(0, s_a, s2_a, mv_a);
  }
  __syncthreads();

  // ---- main loop: 4 tiles, 2 barriers per tile ----
  for(int mt=0; mt<4; mt++){
    if(isG && mt < 3) ln_sum(mt+1, s_a, s2_a, mv_a);  // loads overlap work below
    work();                                           // gemm + epi -> sT
    __syncthreads();                                  // sT complete
    readout(p0 + mt*64);                              // drain sT -> global
    if(isG && mt < 3) ln_norm(mt+1, s_a, s2_a, mv_a); // writes sA for next tile
    __syncthreads();                                  // sA ready, sT free
  }
}

// ---------------- K2: triangle einsum, 128 c-batched 512x512x512 GEMMs ----------------
// t_c[i][j] = sum_k L_c[i][k] * R_c[j][k]; 2048 blocks (XCD-chunk swizzled), tile 128x128, BK=64.
__global__ __launch_bounds__(256) void k2_tri(
    const uint16_t* __restrict__ leftT, const uint16_t* __restrict__ rightT,
    uint16_t* __restrict__ tbuf)
{
  __shared__ uint16_t sm[2*128*64];   // 32KB: sL | sR; reused as [128][128] C-tile in epilogue
  uint16_t* sL = sm;
  uint16_t* sR = sm + 128*64;
  // XCD-chunked bijective swizzle: 2048 = 8 * 256 -> each XCD gets 16 consecutive c-groups
  const int bx = (blockIdx.x & 7)*256 + (blockIdx.x >> 3);
  const int c = bx >> 4, it = (bx >> 2) & 3, jt = bx & 3;
  const uint16_t* L = leftT  + (size_t)c*262144;
  const uint16_t* R = rightT + (size_t)c*262144;
  const int t = threadIdx.x, lane = t & 63, wid = t >> 6;
  const int wm = wid >> 1, wn = wid & 1;   // wave: 64x64 of the 128x128 tile
  const int l15 = lane & 15, lh = lane >> 4;
  const f32x4 z4 = {0.f,0.f,0.f,0.f};
  f32x4 acc[4][4];
#pragma unroll
  for(int a=0;a<4;a++) for(int b=0;b<4;b++) acc[a][b]=z4;

  const int srow = t >> 1, shalf = (t & 1)*64;  // staging: 64B per thread per matrix
  for(int kt=0; kt<8; kt++){
    __syncthreads();
#pragma unroll
    for(int u=0;u<4;u++){
      const int kb = shalf + u*16;                 // byte within the 128B row
      const int ge = kt*64 + (kb >> 1);            // global k element
      const int db = srow*128 + (kb ^ ((srow&7)<<4));
      uint4 va = *(const uint4*)(L + (size_t)(it*128+srow)*512 + ge);
      *(uint4*)((char*)sL + db) = va;
      uint4 vb = *(const uint4*)(R + (size_t)(jt*128+srow)*512 + ge);
      *(uint4*)((char*)sR + db) = vb;
    }
    __syncthreads();
#pragma unroll
    for(int ks=0;ks<2;ks++){
      bf16x8 af[4], bv[4];
#pragma unroll
      for(int tm=0;tm<4;tm++){
        const int row = wm*64 + tm*16 + l15;
        const int byte = row*128 + ((ks*64 + lh*16) ^ ((row&7)<<4));
        af[tm] = *(const bf16x8*)((const char*)sL + byte);
      }
#pragma unroll
      for(int tn=0;tn<4;tn++){
        const int row = wn*64 + tn*16 + l15;
        const int byte = row*128 + ((ks*64 + lh*16) ^ ((row&7)<<4));
        bv[tn] = *(const bf16x8*)((const char*)sR + byte);
      }
#pragma unroll
      for(int tm=0;tm<4;tm++)
#pragma unroll
        for(int tn=0;tn<4;tn++)
          acc[tm][tn] = __builtin_amdgcn_mfma_f32_16x16x32_bf16(af[tm], bv[tn], acc[tm][tn], 0,0,0);
    }
  }
  // epilogue: scatter into LDS [i][j] tile, then coalesced 128B-contiguous stores
  __syncthreads();
#pragma unroll
  for(int tm=0;tm<4;tm++){
#pragma unroll
    for(int tn=0;tn<4;tn++){
      const int j = wn*64 + tn*16 + l15;
#pragma unroll
      for(int r=0;r<4;r++){
        const int i = wm*64 + tm*16 + lh*4 + r;
        const int byte = i*256 + ((j*2) ^ ((i&7)<<4));
        *(uint16_t*)((char*)sm + byte) = f2bf(acc[tm][tn][r]);
      }
    }
  }
  __syncthreads();
  {
    const int i = t >> 1, half = (t & 1)*64;
    uint16_t* dst = tbuf + (size_t)c*262144 + (size_t)(it*128+i)*512 + jt*128 + half;
#pragma unroll
    for(int u=0;u<8;u++){
      const int byte = i*256 + ((half*2 + u*16) ^ ((i&7)<<4));
      *(uint4*)(dst + u*8) = *(const uint4*)((const char*)sm + byte);
    }
  }
}

// ---------------- K3: LN_c + out_proj + gating multiply ----------------
// grid 4096: block owns positions (i, j0..j0+63); reads t and g (both c-major), writes fp32 out.
// Transpose staging: thread owns (8 c x 4 p), packs 16B c-contiguous rows in registers,
// writes 4 ds_write_b128 per matrix (vs 32 ds_write_b16).
__global__ __launch_bounds__(256) void k3_out(
    const uint16_t* __restrict__ tbuf, const uint16_t* __restrict__ gbuf,
    const float* __restrict__ lncw, const float* __restrict__ lncb,
    const uint16_t* __restrict__ wbf, const float* __restrict__ opb,
    float* __restrict__ out)
{
  __shared__ uint16_t sT2[64*128];  // 16KB [p 64][c 128] bf16, swizzled
  __shared__ uint16_t sG[64*128];   // 16KB [p 64][c 128] bf16, swizzled
  const int bx = blockIdx.x;
  const int i = bx >> 3, j0 = (bx & 7)*64;
  const int t = threadIdx.x;
  const int pbase = i*512 + j0;

  { // pack-8 transpose load: thread -> (c0 = (t&15)*8, p0t = (t>>4)*4)
    const int c0 = (t & 15)*8, p0t = (t >> 4)*4;
    uint2 vt[8], vg[8];
#pragma unroll
    for(int r=0;r<8;r++){
      const size_t off = (size_t)(c0+r)*262144 + pbase + p0t;
      vt[r] = *(const uint2*)(tbuf + off);
      vg[r] = *(const uint2*)(gbuf + off);
    }
#pragma unroll
    for(int j=0;j<4;j++){
      const int p = p0t + j;
      uint32_t wt[4], wg[4];
#pragma unroll
      for(int w=0;w<4;w++){
        const uint32_t lot = ((j<2 ? vt[2*w].x   : vt[2*w].y)   >> ((j&1)*16)) & 0xffffu;
        const uint32_t hit = ((j<2 ? vt[2*w+1].x : vt[2*w+1].y) >> ((j&1)*16)) & 0xffffu;
        wt[w] = lot | (hit << 16);
        const uint32_t log = ((j<2 ? vg[2*w].x   : vg[2*w].y)   >> ((j&1)*16)) & 0xffffu;
        const uint32_t hig = ((j<2 ? vg[2*w+1].x : vg[2*w+1].y) >> ((j&1)*16)) & 0xffffu;
        wg[w] = log | (hig << 16);
      }
      const int byte = p*256 + ((c0*2) ^ ((p&7)<<4));
      uint4 qt; qt.x=wt[0]; qt.y=wt[1]; qt.z=wt[2]; qt.w=wt[3];
      uint4 qg; qg.x=wg[0]; qg.y=wg[1]; qg.z=wg[2]; qg.w=wg[3];
      *(uint4*)((char*)sT2 + byte) = qt;
      *(uint4*)((char*)sG  + byte) = qg;
    }
  }
  __syncthreads();

  const int lane = t & 63, wid = t >> 6;
  { // LayerNorm over c per position row (fp32), 4 lanes per row
    const int row = wid*16 + (lane & 15);
    const int q = lane >> 4;
    float xs[32];
#pragma unroll
    for(int u=0;u<4;u++){
      const int kb = q*64 + u*16;
      const int byte = row*256 + (kb ^ ((row&7)<<4));
      uint4 v = *(const uint4*)((const char*)sT2 + byte);
      xs[u*8+0]=bf2f((uint16_t)(v.x&0xffff)); xs[u*8+1]=bf2f((uint16_t)(v.x>>16));
      xs[u*8+2]=bf2f((uint16_t)(v.y&0xffff)); xs[u*8+3]=bf2f((uint16_t)(v.y>>16));
      xs[u*8+4]=bf2f((uint16_t)(v.z&0xffff)); xs[u*8+5]=bf2f((uint16_t)(v.z>>16));
      xs[u*8+6]=bf2f((uint16_t)(v.w&0xffff)); xs[u*8+7]=bf2f((uint16_t)(v.w>>16));
    }
    float s=0.f, s2=0.f;
#pragma unroll
    for(int u=0;u<32;u++){ s += xs[u]; s2 += xs[u]*xs[u]; }
    s  += __shfl_xor(s,16);  s  += __shfl_xor(s,32);
    s2 += __shfl_xor(s2,16); s2 += __shfl_xor(s2,32);
    const float mu   = s * (1.f/128.f);
    const float var  = s2 * (1.f/128.f) - mu*mu;
    const float rstd = rsqrtf(var + LN_EPS);
#pragma unroll
    for(int u=0;u<4;u++){
      const int kb = q*64 + u*16;
      const int c0 = (kb ^ ((row&7)<<4)) >> 1;    // de-swizzled channel of this 16B block
      uint16_t h[8];
#pragma unroll
      for(int j=0;j<8;j++)
        h[j] = f2bf((xs[u*8+j]-mu)*rstd*lncw[c0+j] + lncb[c0+j]);
      uint4 pk;
      pk.x = (uint32_t)h[0] | ((uint32_t)h[1]<<16);
      pk.y = (uint32_t)h[2] | ((uint32_t)h[3]<<16);
      pk.z = (uint32_t)h[4] | ((uint32_t)h[5]<<16);
      pk.w = (uint32_t)h[6] | ((uint32_t)h[7]<<16);
      const int byte = row*256 + (kb ^ ((row&7)<<4));
      *(uint4*)((char*)sT2 + byte) = pk;
    }
  }
  __syncthreads();

  const int wm = wid >> 1, wn = wid & 1;
  const int l15 = lane & 15, lh = lane >> 4;
  const f32x4 z4 = {0.f,0.f,0.f,0.f};
  const uint16_t* W = wbf + 5*16384;   // out_proj_w bf16
  f32x4 acc[2][4];
#pragma unroll
  for(int a=0;a<2;a++) for(int b=0;b<4;b++) acc[a][b]=z4;
#pragma unroll
  for(int ks=0;ks<4;ks++){
    bf16x8 af[2];
#pragma unroll
    for(int tm=0;tm<2;tm++){
      const int row = wm*32 + tm*16 + l15;
      const int byte = row*256 + ((ks*64 + lh*16) ^ ((row&7)<<4));
      af[tm] = *(const bf16x8*)((const char*)sT2 + byte);
    }
#pragma unroll
    for(int tn=0;tn<4;tn++){
      const int o = wn*64 + tn*16 + l15;
      const bf16x8 bv = *(const bf16x8*)(W + o*128 + ks*32 + lh*8);
#pragma unroll
      for(int tm=0;tm<2;tm++)
        acc[tm][tn] = __builtin_amdgcn_mfma_f32_16x16x32_bf16(af[tm], bv, acc[tm][tn], 0,0,0);
    }
  }
#pragma unroll
  for(int tm=0;tm<2;tm++){
#pragma unroll
    for(int tn=0;tn<4;tn++){
      const int col = wn*64 + tn*16 + l15;
      const float obv = opb[col];
#pragma unroll
      for(int r=0;r<4;r++){
        const int row = wm*32 + tm*16 + lh*4 + r;
        const size_t p = (size_t)(pbase + row);
        const int gbyte = row*256 + ((col*2) ^ ((row&7)<<4));
        const float gv = bf2f(*(const uint16_t*)((const char*)sG + gbyte));
        out[p*128 + col] = (acc[tm][tn][r] + obv) * gv;
      }
    }
  }
}

// ---------------- launch ----------------
extern "C" void kernel_launch(void* const* d_in, const int* in_sizes, int n_in,
                              void* d_out, int out_size, void* d_ws, size_t ws_size,
                              hipStream_t stream)
{
  (void)in_sizes; (void)n_in; (void)out_size; (void)ws_size;
  const float* act   = (const float*)d_in[0];
  const float* mask  = (const float*)d_in[1];
  const float* lnw   = (const float*)d_in[2];
  const float* lnb   = (const float*)d_in[3];
  const float* lpw   = (const float*)d_in[4];
  const float* lpb   = (const float*)d_in[5];
  const float* rpw   = (const float*)d_in[6];
  const float* rpb   = (const float*)d_in[7];
  const float* lgw   = (const float*)d_in[8];
  const float* lgb   = (const float*)d_in[9];
  const float* rgw   = (const float*)d_in[10];
  const float* rgb   = (const float*)d_in[11];
  const float* lncw  = (const float*)d_in[12];
  const float* lncb  = (const float*)d_in[13];
  const float* opw   = (const float*)d_in[14];
  const float* opb   = (const float*)d_in[15];
  const float* gw    = (const float*)d_in[16];
  const float* gb    = (const float*)d_in[17];

  char* ws = (char*)d_ws;
  uint16_t* leftT  = (uint16_t*)(ws);                      // 64MB [C][N*N] bf16
  uint16_t* rightT = (uint16_t*)(ws + ((size_t)64<<20));   // 64MB
  uint16_t* gbuf   = (uint16_t*)(ws + ((size_t)128<<20));  // 64MB [C][N*N] bf16 (c-major)
  uint16_t* tbuf   = (uint16_t*)(ws + ((size_t)192<<20));  // 64MB [C][N*N] bf16
  uint16_t* wbf    = (uint16_t*)(ws + ((size_t)256<<20));  // 192KB: 6 bf16 weight mats

  wconv_k<<<384, 256, 0, stream>>>(lpw, lgw, rpw, rgw, gw, opw, wbf);
  k1_proj<<<1024, 768, 0, stream>>>(act, mask, lnw, lnb, lpb, lgb, rpb, rgb, gb,
                                    wbf, leftT, rightT, gbuf);
  k2_tri<<<2048, 256, 0, stream>>>(leftT, rightT, tbuf);
  k3_out<<<4096, 256, 0, stream>>>(tbuf, gbuf, lncw, lncb, wbf, opb, (float*)d_out);
}

// Round 6
// 354.585 us; speedup vs baseline: 1.9494x; 1.9494x over previous
//
#include <hip/hip_runtime.h>
#include <cstdint>
#include <cstddef>

#define LN_EPS 1e-5f

typedef short bf16x8 __attribute__((ext_vector_type(8)));
typedef float f32x4 __attribute__((ext_vector_type(4)));

__device__ __forceinline__ uint16_t f2bf(float f){
  uint32_t u = __float_as_uint(f);
  u += 0x7fffu + ((u >> 16) & 1u);
  return (uint16_t)(u >> 16);
}
__device__ __forceinline__ float bf2f(uint16_t h){
  return __uint_as_float(((uint32_t)h) << 16);
}
__device__ __forceinline__ float sigm(float x){
  return __builtin_amdgcn_rcpf(1.0f + __expf(-x));
}

// ---------------- K0: convert 6 weight matrices (128x128 fp32) to bf16 ----------------
// order: 0=left_proj_w 1=left_gate_w 2=right_proj_w 3=right_gate_w 4=gating_w 5=out_proj_w
__global__ __launch_bounds__(256) void wconv_k(
    const float* __restrict__ w0, const float* __restrict__ w1,
    const float* __restrict__ w2, const float* __restrict__ w3,
    const float* __restrict__ w4, const float* __restrict__ w5,
    uint16_t* __restrict__ dst)
{
  int i = blockIdx.x*256 + threadIdx.x;   // 6*16384 total
  int m = i >> 14, e = i & 16383;
  const float* s = (m==0)?w0:(m==1)?w1:(m==2)?w2:(m==3)?w3:(m==4)?w4:w5;
  dst[i] = f2bf(s[e]);
}

// ---------------- K1: LN + 5 projections, wave-specialized, W-in-registers ----------------
// 1024 blocks x 768 threads (12 waves); block owns 256 rows as 4 tiles of 64.
// Waves 0-3: left proj+gate; 4-7: right; 8-11: gating + LN of next tile.
// LN is sum/norm split: only (s, s2, mask) live across work() -> no spill; norm pass
// re-reads act from L1. Double-buffered sA/sT, 1 barrier per tile (R4 schedule).
// NOTE: __launch_bounds__(768,3) — do NOT raise min-waves; W-persistent needs ~110+ VGPRs
// and a tighter cap spills W to scratch (R5: FETCH 73MB->1.37GB, 185us->520us).
__global__ __launch_bounds__(768, 3) void k1_proj(
    const float* __restrict__ act, const float* __restrict__ mask,
    const float* __restrict__ lnw, const float* __restrict__ lnb,
    const float* __restrict__ lpb, const float* __restrict__ lgB,
    const float* __restrict__ rpb, const float* __restrict__ rgB,
    const float* __restrict__ gB,
    const uint16_t* __restrict__ wbf,
    uint16_t* __restrict__ leftT, uint16_t* __restrict__ rightT,
    uint16_t* __restrict__ gbuf)
{
  __shared__ uint16_t sA[2][64*128];      // 32KB, [row64][c128] bf16 swizzled
  __shared__ uint16_t sT[2][3][128*64];   // 96KB, [c128][p64] bf16 swizzled
  __shared__ float sMask[2][64];
  const int t = threadIdx.x;
  const int lane = t & 63, wid = t >> 6;
  const int p0 = blockIdx.x * 256;
  const int l15 = lane & 15, lh = lane >> 4;
  const bool isG = (wid >= 8);
  const int fam = wid >> 2;               // 0=L, 1=R, 2=G
  const int cbase = (wid & 3) * 32;
  const f32x4 z4 = {0.f,0.f,0.f,0.f};

  // ---- persistent W fragments (loaded once) ----
  bf16x8 Wp[2][4], Wg[2][4];
  {
    const int m0 = (fam==0)?0:(fam==1)?2:4;
#pragma unroll
    for(int tn=0;tn<2;tn++){
      const int o = cbase + tn*16 + l15;
#pragma unroll
      for(int ks=0;ks<4;ks++)
        Wp[tn][ks] = *(const bf16x8*)(wbf + m0*16384 + o*128 + ks*32 + lh*8);
    }
    if(!isG){
#pragma unroll
      for(int tn=0;tn<2;tn++){
        const int o = cbase + tn*16 + l15;
#pragma unroll
        for(int ks=0;ks<4;ks++)
          Wg[tn][ks] = *(const bf16x8*)(wbf + (m0+1)*16384 + o*128 + ks*32 + lh*8);
      }
    }
  }
  // ---- biases (persistent scalars) ----
  float pbv[2], gbv[2];
  {
    const float* pb  = (fam==0)? lpb : (fam==1)? rpb : gB;
    const float* gb2 = (fam==0)? lgB : rgB;
#pragma unroll
    for(int tn=0;tn<2;tn++){
      const int c = cbase + tn*16 + l15;
      pbv[tn] = pb[c];
      gbv[tn] = isG ? 0.f : gb2[c];
    }
  }

  // ---- G-wave LN: sum pass (keeps only s,s2,mv live) ----
  auto ln_sum = [&](int tile, float& s, float& s2, float& mv){
    const int g = t - 512, row = g >> 2, q = g & 3;
    const float* src = act + (size_t)(p0 + tile*64 + row)*128 + q*32;
    s = 0.f; s2 = 0.f;
#pragma unroll
    for(int u=0;u<8;u++){
      float4 v = *(const float4*)(src + u*4);
      s  += v.x + v.y + v.z + v.w;
      s2 += v.x*v.x + v.y*v.y + v.z*v.z + v.w*v.w;
    }
    s  += __shfl_xor(s,1);  s  += __shfl_xor(s,2);
    s2 += __shfl_xor(s2,1); s2 += __shfl_xor(s2,2);
    if(q==0) mv = mask[p0 + tile*64 + row];
  };
  // ---- G-wave LN: normalize pass (re-reads act from L1) ----
  auto ln_norm = [&](int tile, float s, float s2, float mv, int nb){
    const int g = t - 512, row = g >> 2, q = g & 3;
    const float* src = act + (size_t)(p0 + tile*64 + row)*128 + q*32;
    const float mu   = s * (1.f/128.f);
    const float var  = s2 * (1.f/128.f) - mu*mu;
    const float rstd = rsqrtf(var + LN_EPS);
    const int rs = (row&7)<<4;
#pragma unroll
    for(int u=0;u<4;u++){
      const int c0 = q*32 + u*8;
      float4 a0 = *(const float4*)(src + u*8);
      float4 a1 = *(const float4*)(src + u*8 + 4);
      float4 w0 = *(const float4*)(lnw + c0), w1 = *(const float4*)(lnw + c0 + 4);
      float4 b0 = *(const float4*)(lnb + c0), b1 = *(const float4*)(lnb + c0 + 4);
      uint16_t h[8];
      h[0]=f2bf((a0.x-mu)*rstd*w0.x+b0.x); h[1]=f2bf((a0.y-mu)*rstd*w0.y+b0.y);
      h[2]=f2bf((a0.z-mu)*rstd*w0.z+b0.z); h[3]=f2bf((a0.w-mu)*rstd*w0.w+b0.w);
      h[4]=f2bf((a1.x-mu)*rstd*w1.x+b1.x); h[5]=f2bf((a1.y-mu)*rstd*w1.y+b1.y);
      h[6]=f2bf((a1.z-mu)*rstd*w1.z+b1.z); h[7]=f2bf((a1.w-mu)*rstd*w1.w+b1.w);
      uint4 pk;
      pk.x = (uint32_t)h[0] | ((uint32_t)h[1]<<16);
      pk.y = (uint32_t)h[2] | ((uint32_t)h[3]<<16);
      pk.z = (uint32_t)h[4] | ((uint32_t)h[5]<<16);
      pk.w = (uint32_t)h[6] | ((uint32_t)h[7]<<16);
      *(uint4*)((char*)sA[nb] + row*256 + ((c0*2) ^ rs)) = pk;
    }
    if(q==0) sMask[nb][row] = mv;
  };

  // ---- gemm + fused epilogue for one 64-row tile ----
  auto work = [&](int cb){
    uint16_t* sTf = sT[cb][fam];
#pragma unroll
    for(int rt=0; rt<4; rt++){
      bf16x8 af[4];
      const int arow = rt*16 + l15;
      const int ars = (arow&7)<<4;
#pragma unroll
      for(int ks=0;ks<4;ks++)
        af[ks] = *(const bf16x8*)((const char*)sA[cb] + arow*256 + ((ks*64+lh*16) ^ ars));
      f32x4 aP[2] = {z4,z4}, aQ[2] = {z4,z4};
      if(isG){
#pragma unroll
        for(int ks=0;ks<4;ks++)
#pragma unroll
          for(int tn=0;tn<2;tn++)
            aP[tn] = __builtin_amdgcn_mfma_f32_16x16x32_bf16(af[ks], Wp[tn][ks], aP[tn], 0,0,0);
      } else {
#pragma unroll
        for(int ks=0;ks<4;ks++)
#pragma unroll
          for(int tn=0;tn<2;tn++){
            aP[tn] = __builtin_amdgcn_mfma_f32_16x16x32_bf16(af[ks], Wp[tn][ks], aP[tn], 0,0,0);
            aQ[tn] = __builtin_amdgcn_mfma_f32_16x16x32_bf16(af[ks], Wg[tn][ks], aQ[tn], 0,0,0);
          }
      }
      const int prow = rt*16 + lh*4;
      const int poff = prow*2;
#pragma unroll
      for(int tn=0;tn<2;tn++){
        const int c = cbase + tn*16 + l15;
        uint16_t h[4];
        if(isG){
#pragma unroll
          for(int r=0;r<4;r++)
            h[r] = f2bf(sigm(aP[tn][r] + pbv[tn]));
        } else {
#pragma unroll
          for(int r=0;r<4;r++)
            h[r] = f2bf(sMask[cb][prow+r]*(aP[tn][r]+pbv[tn]) * sigm(aQ[tn][r]+gbv[tn]));
        }
        uint2 pk;
        pk.x = (uint32_t)h[0] | ((uint32_t)h[1]<<16);
        pk.y = (uint32_t)h[2] | ((uint32_t)h[3]<<16);
        *(uint2*)((char*)sTf + c*128 + (poff ^ ((c&7)<<4))) = pk;
      }
    }
  };

  // ---- coalesced c-major readout of one sT buffer (all 12 waves) ----
  auto readout = [&](int sb, int pbase){
    const int oi = t >> 8;                // 0=L,1=R,2=G
    const int c = (t >> 1) & 127;
    const int ph = (t & 1) * 32;
    const int cs = (c&7) << 4;
    const char* src = (const char*)sT[sb][oi];
    uint4 q[4];
#pragma unroll
    for(int u=0;u<4;u++)
      q[u] = *(const uint4*)(src + c*128 + ((ph*2 + u*16) ^ cs));
    uint16_t* base = (oi==0)? leftT : (oi==1)? rightT : gbuf;
    uint16_t* dst = base + (size_t)c*262144 + pbase + ph;
    *(uint4*)(dst+ 0)=q[0]; *(uint4*)(dst+ 8)=q[1];
    *(uint4*)(dst+16)=q[2]; *(uint4*)(dst+24)=q[3];
  };

  float s_a = 0.f, s2_a = 0.f, mv_a = 0.f;

  // ---- prologue: G waves LN tile 0 into buffer 0 ----
  if(isG){
    ln_sum(0, s_a, s2_a, mv_a);
    ln_norm(0, s_a, s2_a, mv_a, 0);
  }
  __syncthreads();

  // ---- main loop: 4 tiles, 1 barrier per tile ----
  for(int mt=0; mt<4; mt++){
    const int cb = mt & 1;
    if(isG && mt < 3) ln_sum(mt+1, s_a, s2_a, mv_a);   // global loads overlap below
    if(mt > 0) readout(cb^1, p0 + (mt-1)*64);          // drain previous tile
    work(cb);                                          // gemm + epi -> sT[cb]
    if(isG && mt < 3) ln_norm(mt+1, s_a, s2_a, mv_a, cb^1); // sA for next tile
    __syncthreads();
  }
  readout(1, p0 + 192);                                // tile 3 lives in sT[1]
}

// ---------------- K2: triangle einsum, 128 c-batched 512x512x512 GEMMs ----------------
// t_c[i][j] = sum_k L_c[i][k] * R_c[j][k]; 2048 blocks (XCD-chunk swizzled), tile 128x128, BK=64.
__global__ __launch_bounds__(256) void k2_tri(
    const uint16_t* __restrict__ leftT, const uint16_t* __restrict__ rightT,
    uint16_t* __restrict__ tbuf)
{
  __shared__ uint16_t sm[2*128*64];   // 32KB: sL | sR; reused as [128][128] C-tile in epilogue
  uint16_t* sL = sm;
  uint16_t* sR = sm + 128*64;
  // XCD-chunked bijective swizzle: 2048 = 8 * 256 -> each XCD gets 16 consecutive c-groups
  const int bx = (blockIdx.x & 7)*256 + (blockIdx.x >> 3);
  const int c = bx >> 4, it = (bx >> 2) & 3, jt = bx & 3;
  const uint16_t* L = leftT  + (size_t)c*262144;
  const uint16_t* R = rightT + (size_t)c*262144;
  const int t = threadIdx.x, lane = t & 63, wid = t >> 6;
  const int wm = wid >> 1, wn = wid & 1;   // wave: 64x64 of the 128x128 tile
  const int l15 = lane & 15, lh = lane >> 4;
  const f32x4 z4 = {0.f,0.f,0.f,0.f};
  f32x4 acc[4][4];
#pragma unroll
  for(int a=0;a<4;a++) for(int b=0;b<4;b++) acc[a][b]=z4;

  const int srow = t >> 1, shalf = (t & 1)*64;  // staging: 64B per thread per matrix
  for(int kt=0; kt<8; kt++){
    __syncthreads();
#pragma unroll
    for(int u=0;u<4;u++){
      const int kb = shalf + u*16;                 // byte within the 128B row
      const int ge = kt*64 + (kb >> 1);            // global k element
      const int db = srow*128 + (kb ^ ((srow&7)<<4));
      uint4 va = *(const uint4*)(L + (size_t)(it*128+srow)*512 + ge);
      *(uint4*)((char*)sL + db) = va;
      uint4 vb = *(const uint4*)(R + (size_t)(jt*128+srow)*512 + ge);
      *(uint4*)((char*)sR + db) = vb;
    }
    __syncthreads();
#pragma unroll
    for(int ks=0;ks<2;ks++){
      bf16x8 af[4], bv[4];
#pragma unroll
      for(int tm=0;tm<4;tm++){
        const int row = wm*64 + tm*16 + l15;
        const int byte = row*128 + ((ks*64 + lh*16) ^ ((row&7)<<4));
        af[tm] = *(const bf16x8*)((const char*)sL + byte);
      }
#pragma unroll
      for(int tn=0;tn<4;tn++){
        const int row = wn*64 + tn*16 + l15;
        const int byte = row*128 + ((ks*64 + lh*16) ^ ((row&7)<<4));
        bv[tn] = *(const bf16x8*)((const char*)sR + byte);
      }
#pragma unroll
      for(int tm=0;tm<4;tm++)
#pragma unroll
        for(int tn=0;tn<4;tn++)
          acc[tm][tn] = __builtin_amdgcn_mfma_f32_16x16x32_bf16(af[tm], bv[tn], acc[tm][tn], 0,0,0);
    }
  }
  // epilogue: scatter into LDS [i][j] tile, then coalesced 128B-contiguous stores
  __syncthreads();
#pragma unroll
  for(int tm=0;tm<4;tm++){
#pragma unroll
    for(int tn=0;tn<4;tn++){
      const int j = wn*64 + tn*16 + l15;
#pragma unroll
      for(int r=0;r<4;r++){
        const int i = wm*64 + tm*16 + lh*4 + r;
        const int byte = i*256 + ((j*2) ^ ((i&7)<<4));
        *(uint16_t*)((char*)sm + byte) = f2bf(acc[tm][tn][r]);
      }
    }
  }
  __syncthreads();
  {
    const int i = t >> 1, half = (t & 1)*64;
    uint16_t* dst = tbuf + (size_t)c*262144 + (size_t)(it*128+i)*512 + jt*128 + half;
#pragma unroll
    for(int u=0;u<8;u++){
      const int byte = i*256 + ((half*2 + u*16) ^ ((i&7)<<4));
      *(uint4*)(dst + u*8) = *(const uint4*)((const char*)sm + byte);
    }
  }
}

// ---------------- K3: LN_c + out_proj + gating multiply ----------------
// grid 4096: block owns positions (i, j0..j0+63); reads t and g (both c-major), writes fp32 out.
__global__ __launch_bounds__(256) void k3_out(
    const uint16_t* __restrict__ tbuf, const uint16_t* __restrict__ gbuf,
    const float* __restrict__ lncw, const float* __restrict__ lncb,
    const uint16_t* __restrict__ wbf, const float* __restrict__ opb,
    float* __restrict__ out)
{
  __shared__ uint16_t sT2[64*128];  // 16KB [p 64][c 128] bf16, swizzled
  __shared__ uint16_t sG[64*128];   // 16KB [p 64][c 128] bf16, swizzled
  const int bx = blockIdx.x;
  const int i = bx >> 3, j0 = (bx & 7)*64;
  const int t = threadIdx.x;
  const int pbase = i*512 + j0;

  { // transpose-load t and g: thread -> (c = t>>1, 32 consecutive j), 64B coalesced reads
    const int c = t >> 1, ph = (t & 1)*32;
    const uint16_t* srcT = tbuf + (size_t)c*262144 + pbase + ph;
    const uint16_t* srcG = gbuf + (size_t)c*262144 + pbase + ph;
#pragma unroll
    for(int u=0;u<4;u++){
      uint4 v = *(const uint4*)(srcT + u*8);
      uint4 g = *(const uint4*)(srcG + u*8);
      uint16_t et[8], eg[8];
      et[0]=(uint16_t)(v.x&0xffff); et[1]=(uint16_t)(v.x>>16);
      et[2]=(uint16_t)(v.y&0xffff); et[3]=(uint16_t)(v.y>>16);
      et[4]=(uint16_t)(v.z&0xffff); et[5]=(uint16_t)(v.z>>16);
      et[6]=(uint16_t)(v.w&0xffff); et[7]=(uint16_t)(v.w>>16);
      eg[0]=(uint16_t)(g.x&0xffff); eg[1]=(uint16_t)(g.x>>16);
      eg[2]=(uint16_t)(g.y&0xffff); eg[3]=(uint16_t)(g.y>>16);
      eg[4]=(uint16_t)(g.z&0xffff); eg[5]=(uint16_t)(g.z>>16);
      eg[6]=(uint16_t)(g.w&0xffff); eg[7]=(uint16_t)(g.w>>16);
#pragma unroll
      for(int k2=0;k2<8;k2++){
        const int p = ph + u*8 + k2;
        const int byte = p*256 + ((c*2) ^ ((p&7)<<4));
        *(uint16_t*)((char*)sT2 + byte) = et[k2];
        *(uint16_t*)((char*)sG + byte) = eg[k2];
      }
    }
  }
  __syncthreads();

  const int lane = t & 63, wid = t >> 6;
  { // LayerNorm over c per position row (fp32), 4 lanes per row
    const int row = wid*16 + (lane & 15);
    const int q = lane >> 4;
    float xs[32];
#pragma unroll
    for(int u=0;u<4;u++){
      const int kb = q*64 + u*16;
      const int byte = row*256 + (kb ^ ((row&7)<<4));
      uint4 v = *(const uint4*)((const char*)sT2 + byte);
      xs[u*8+0]=bf2f((uint16_t)(v.x&0xffff)); xs[u*8+1]=bf2f((uint16_t)(v.x>>16));
      xs[u*8+2]=bf2f((uint16_t)(v.y&0xffff)); xs[u*8+3]=bf2f((uint16_t)(v.y>>16));
      xs[u*8+4]=bf2f((uint16_t)(v.z&0xffff)); xs[u*8+5]=bf2f((uint16_t)(v.z>>16));
      xs[u*8+6]=bf2f((uint16_t)(v.w&0xffff)); xs[u*8+7]=bf2f((uint16_t)(v.w>>16));
    }
    float s=0.f, s2=0.f;
#pragma unroll
    for(int u=0;u<32;u++){ s += xs[u]; s2 += xs[u]*xs[u]; }
    s  += __shfl_xor(s,16);  s  += __shfl_xor(s,32);
    s2 += __shfl_xor(s2,16); s2 += __shfl_xor(s2,32);
    const float mu   = s * (1.f/128.f);
    const float var  = s2 * (1.f/128.f) - mu*mu;
    const float rstd = rsqrtf(var + LN_EPS);
#pragma unroll
    for(int u=0;u<4;u++){
      const int kb = q*64 + u*16;
      const int c0 = (kb ^ ((row&7)<<4)) >> 1;    // de-swizzled channel of this 16B block
      uint16_t h[8];
#pragma unroll
      for(int j=0;j<8;j++)
        h[j] = f2bf((xs[u*8+j]-mu)*rstd*lncw[c0+j] + lncb[c0+j]);
      uint4 pk;
      pk.x = (uint32_t)h[0] | ((uint32_t)h[1]<<16);
      pk.y = (uint32_t)h[2] | ((uint32_t)h[3]<<16);
      pk.z = (uint32_t)h[4] | ((uint32_t)h[5]<<16);
      pk.w = (uint32_t)h[6] | ((uint32_t)h[7]<<16);
      const int byte = row*256 + (kb ^ ((row&7)<<4));
      *(uint4*)((char*)sT2 + byte) = pk;
    }
  }
  __syncthreads();

  const int wm = wid >> 1, wn = wid & 1;
  const int l15 = lane & 15, lh = lane >> 4;
  const f32x4 z4 = {0.f,0.f,0.f,0.f};
  const uint16_t* W = wbf + 5*16384;   // out_proj_w bf16
  f32x4 acc[2][4];
#pragma unroll
  for(int a=0;a<2;a++) for(int b=0;b<4;b++) acc[a][b]=z4;
#pragma unroll
  for(int ks=0;ks<4;ks++){
    bf16x8 af[2];
#pragma unroll
    for(int tm=0;tm<2;tm++){
      const int row = wm*32 + tm*16 + l15;
      const int byte = row*256 + ((ks*64 + lh*16) ^ ((row&7)<<4));
      af[tm] = *(const bf16x8*)((const char*)sT2 + byte);
    }
#pragma unroll
    for(int tn=0;tn<4;tn++){
      const int o = wn*64 + tn*16 + l15;
      const bf16x8 bv = *(const bf16x8*)(W + o*128 + ks*32 + lh*8);
#pragma unroll
      for(int tm=0;tm<2;tm++)
        acc[tm][tn] = __builtin_amdgcn_mfma_f32_16x16x32_bf16(af[tm], bv, acc[tm][tn], 0,0,0);
    }
  }
#pragma unroll
  for(int tm=0;tm<2;tm++){
#pragma unroll
    for(int tn=0;tn<4;tn++){
      const int col = wn*64 + tn*16 + l15;
      const float obv = opb[col];
#pragma unroll
      for(int r=0;r<4;r++){
        const int row = wm*32 + tm*16 + lh*4 + r;
        const size_t p = (size_t)(pbase + row);
        const int gbyte = row*256 + ((col*2) ^ ((row&7)<<4));
        const float gv = bf2f(*(const uint16_t*)((const char*)sG + gbyte));
        out[p*128 + col] = (acc[tm][tn][r] + obv) * gv;
      }
    }
  }
}

// ---------------- launch ----------------
extern "C" void kernel_launch(void* const* d_in, const int* in_sizes, int n_in,
                              void* d_out, int out_size, void* d_ws, size_t ws_size,
                              hipStream_t stream)
{
  (void)in_sizes; (void)n_in; (void)out_size; (void)ws_size;
  const float* act   = (const float*)d_in[0];
  const float* mask  = (const float*)d_in[1];
  const float* lnw   = (const float*)d_in[2];
  const float* lnb   = (const float*)d_in[3];
  const float* lpw   = (const float*)d_in[4];
  const float* lpb   = (const float*)d_in[5];
  const float* rpw   = (const float*)d_in[6];
  const float* rpb   = (const float*)d_in[7];
  const float* lgw   = (const float*)d_in[8];
  const float* lgb   = (const float*)d_in[9];
  const float* rgw   = (const float*)d_in[10];
  const float* rgb   = (const float*)d_in[11];
  const float* lncw  = (const float*)d_in[12];
  const float* lncb  = (const float*)d_in[13];
  const float* opw   = (const float*)d_in[14];
  const float* opb   = (const float*)d_in[15];
  const float* gw    = (const float*)d_in[16];
  const float* gb    = (const float*)d_in[17];

  char* ws = (char*)d_ws;
  uint16_t* leftT  = (uint16_t*)(ws);                      // 64MB [C][N*N] bf16
  uint16_t* rightT = (uint16_t*)(ws + ((size_t)64<<20));   // 64MB
  uint16_t* gbuf   = (uint16_t*)(ws + ((size_t)128<<20));  // 64MB [C][N*N] bf16 (c-major)
  uint16_t* tbuf   = (uint16_t*)(ws + ((size_t)192<<20));  // 64MB [C][N*N] bf16
  uint16_t* wbf    = (uint16_t*)(ws + ((size_t)256<<20));  // 192KB: 6 bf16 weight mats

  wconv_k<<<384, 256, 0, stream>>>(lpw, lgw, rpw, rgw, gw, opw, wbf);
  k1_proj<<<1024, 768, 0, stream>>>(act, mask, lnw, lnb, lpb, lgb, rpb, rgb, gb,
                                    wbf, leftT, rightT, gbuf);
  k2_tri<<<2048, 256, 0, stream>>>(leftT, rightT, tbuf);
  k3_out<<<4096, 256, 0, stream>>>(tbuf, gbuf, lncw, lncb, wbf, opb, (float*)d_out);
}